// Round 14
// baseline (2697.947 us; speedup 1.0000x reference)
//
#include <hip/hip_runtime.h>

// Problem constants: B=1, C=2, H=W=64, m=8192, mk=64, K1=K2=36, K3=2, Kc=2592, iters=6 (5 steps).
#define KC 2592
#define KCP 2624           // padded NtT row stride (zeros in tail)
#define HW 4096

// workspace layout (float offsets), total 2818048 floats = 11.27 MB
#define OFF_L    0u
#define OFF_S    8192u
#define OFF_MT   16384u    // Mt[64][8192]
#define OFF_NTT  540672u   // NtT[64][2624], layout d=(kk*36+ii)*36+jj, cols 2592..2623 zero
#define OFF_BIG  708608u   // Rpart[256][8192] / T1t[256][8192] / (T2part[8][64][2592] + T2sum[64][2592])
#define OFF_GRAM 2805760u  // raw gram 64x64 (shared by Cm and Cn phases)
#define OFF_CMI  2809856u
#define OFF_CNI  2813952u

__global__ __launch_bounds__(256) void k_init(const float* __restrict__ inp, const float* __restrict__ s0,
                                              float* __restrict__ L, float* __restrict__ S,
                                              float* __restrict__ Mt, float* __restrict__ NtT){
  int t = blockIdx.x * 256 + threadIdx.x;
  if (t < 8192){ L[t] = inp[t]; S[t] = s0[t]; }
  if (t < 524288){ int r = t >> 13; int p = t & 8191; Mt[t] = (p == r) ? 1.0f : 0.0f; }
  if (t < 167936){ int r = t / KCP; int d = t - r * KCP;
                   int dr = (r % 36) * 36 + r / 36;   // N0: d=(0*36+ii)*36+jj with col=jj*36+ii=r
                   NtT[t] = (d == dr) ? 1.0f : 0.0f; }
}

// ---- SINGLE-WAVE rolled LDS Jordan-exchange inverse of (2g*gram + a*I), SPD, no pivoting.
// Synthesis of 7 rounds of evidence: (a) unrolled bodies are icache-streaming (~9 cyc/instr,
// R6 FETCH=127KB) -> must be ROLLED; (b) __syncthreads in a block-divergent sentinel branch
// destroys the HOST conv's codegen (R10/R12: VGPR 76->52, 28->177us; barrier-free R7-R9 kept
// VGPR 76) -> must be BARRIER-FREE. Single wave = wave-synchronous LDS, no barriers, ~2KB code.
// Lane c owns column c of A[64][64] (stride 64: per-instruction lane addresses contiguous ->
// conflict-free; broadcasts free). ~130 independent LDS ops/pivot, pipelined -> ~10-20us total,
// hidden under the host conv's ~28us. Math identical to R11/R12's verified Jordan exchange.
__device__ void inv64_wave(const float* __restrict__ src, const float* __restrict__ pg,
                           const float* __restrict__ pa, float* __restrict__ dst,
                           int lane, float* __restrict__ A){
  float scale = 2.0f * pg[0], ad = pa[0];
  #pragma unroll 4
  for (int i = 0; i < 64; i++)
    A[i * 64 + lane] = scale * src[i * 64 + lane] + ((i == lane) ? ad : 0.0f);
  #pragma unroll 1
  for (int j = 0; j < 64; j++){
    float p = 1.0f / A[j * 64 + j];      // broadcast read (wave-synchronous, no barrier)
    float rc = A[j * 64 + lane];         // old row j, this lane's column
    bool cj = (lane == j);
    float rcp = rc * p;
    float pivrow = cj ? p : rcp;         // new row j
    #pragma unroll 4
    for (int i = 0; i < 64; i++){
      float fi = A[i * 64 + j];          // old col j entry (broadcast; read-before-write in-iter)
      float old = A[i * 64 + lane];
      float nonpiv = cj ? (-fi * p) : fmaf(-fi, rcp, old);
      A[i * 64 + lane] = (i == j) ? pivrow : nonpiv;
    }
  }
  #pragma unroll 4
  for (int i = 0; i < 64; i++)
    dst[i * 64 + lane] = A[i * 64 + lane];
}

// ---- conv_R (+ fused FULL inv(Cm) as sentinel z==4, single-wave barrier-free):
// Rpart[r+64z][p] = sum_{kk, ii in 9-quarter z, jj} Mt[r][(c+kk)%2][(h+ii)%64][(w+jj)%64] * f[kk][ii][jj]
__global__ __launch_bounds__(128) void k_conv_R(const float* __restrict__ Mtg,
                                                const float* __restrict__ NtT,
                                                float* __restrict__ Rpart,
                                                const float* __restrict__ Gr,
                                                const float* __restrict__ pg,
                                                const float* __restrict__ pa,
                                                float* __restrict__ CmI){
  __shared__ float smem[4096];   // union: conv uses 3912 floats (img 3264 + filt 648); inv A uses 4096
  if (blockIdx.z == 4){
    if (blockIdx.x == 0 && blockIdx.y == 0 && threadIdx.x < 64)
      inv64_wave(Gr, pg, pa, CmI, threadIdx.x, smem);
    return;
  }
  float (*img)[24][68] = (float(*)[24][68])smem;       // [2][24][68]
  float4* filt4 = (float4*)(smem + 3264);              // [162], byte offset 13056 (16B aligned)
  int r = blockIdx.x, oct = blockIdx.y, z = blockIdx.z, tid = threadIdx.x;
  int rowbase = oct * 16 + z * 9;
  const float4* gi4 = (const float4*)(Mtg + (size_t)r * 8192);
  for (int t = tid; t < 768; t += 128){
    int fw = t & 15, rr = t >> 4;
    int c = (rr >= 24) ? 1 : 0, q = rr - c * 24;
    int gr = (rowbase + q) & 63;
    float4 v4 = gi4[(c * 64 + gr) * 16 + fw];
    float* d = &img[c][q][fw * 4];
    d[0] = v4.x; d[1] = v4.y; d[2] = v4.z; d[3] = v4.w;
  }
  int iilo = z * 9;
  const float* gf = NtT + (size_t)r * KCP;
  for (int t = tid; t < 162; t += 128){
    int kk = t / 81; int rem4 = t - kk * 81;
    filt4[t] = *(const float4*)(gf + kk * 1296 + iilo * 36 + rem4 * 4);
  }
  __syncthreads();
  int c0 = tid >> 6, hl = (tid >> 2) & 15, w0 = (tid & 3) * 16;
  float acc[16];
  #pragma unroll
  for (int u = 0; u < 16; u++) acc[u] = 0.0f;
  #pragma unroll 1
  for (int kk = 0; kk < 2; kk++){
    int cimg = (c0 + kk) & 1;
    #pragma unroll 1
    for (int iix = 0; iix < 9; iix++){
      const float* ib = img[cimg][hl + iix];
      float v[32];
      #pragma unroll
      for (int t = 0; t < 8; t++){
        float4 t4 = *(const float4*)&ib[(w0 + 4 * t) & 63];
        v[4*t] = t4.x; v[4*t+1] = t4.y; v[4*t+2] = t4.z; v[4*t+3] = t4.w;
      }
      const float4* fb = &filt4[kk * 81 + iix * 9];
      #pragma unroll
      for (int g = 0; g < 9; g++){
        float4 ff = fb[g];
        #pragma unroll
        for (int u = 0; u < 16; u++) acc[u] = fmaf(ff.x, v[(4*g + 0 + u) & 31], acc[u]);
        #pragma unroll
        for (int u = 0; u < 16; u++) acc[u] = fmaf(ff.y, v[(4*g + 1 + u) & 31], acc[u]);
        #pragma unroll
        for (int u = 0; u < 16; u++) acc[u] = fmaf(ff.z, v[(4*g + 2 + u) & 31], acc[u]);
        #pragma unroll
        for (int u = 0; u < 16; u++) acc[u] = fmaf(ff.w, v[(4*g + 3 + u) & 31], acc[u]);
        if (g < 5){
          float4 nv = *(const float4*)&ib[(w0 + 32 + 4*g) & 63];
          int s = (4*g) & 31;
          v[s] = nv.x; v[s+1] = nv.y; v[s+2] = nv.z; v[s+3] = nv.w;
        }
      }
    }
  }
  int h = oct * 16 + hl;
  size_t ob = ((size_t)r + 64 * z) * 8192 + (size_t)(c0 * HW + h * 64 + w0);
  *(float4*)&Rpart[ob]      = make_float4(acc[0], acc[1], acc[2], acc[3]);
  *(float4*)&Rpart[ob + 4]  = make_float4(acc[4], acc[5], acc[6], acc[7]);
  *(float4*)&Rpart[ob + 8]  = make_float4(acc[8], acc[9], acc[10], acc[11]);
  *(float4*)&Rpart[ob + 12] = make_float4(acc[12], acc[13], acc[14], acc[15]);
}

// ---- conv_T1 (pure): T1t[r+64z][p] = sum L[(c-kk)%2][(h-ii)%64][(w-jj)%64] * f[kk][ii][jj]
__global__ __launch_bounds__(128) void k_conv_T1(const float* __restrict__ Lg,
                                                 const float* __restrict__ NtT,
                                                 float* __restrict__ T1t){
  __shared__ float img[2][24][68];
  __shared__ float4 filt4[162];
  int r = blockIdx.x, oct = blockIdx.y, z = blockIdx.z, tid = threadIdx.x;
  int rowbase = (oct * 16 - z * 9 - 8 + 128) & 63;     // stored q <-> global row (rowbase+q)&63
  const float4* gi4 = (const float4*)Lg;
  for (int t = tid; t < 768; t += 128){
    int fw = t & 15, rr = t >> 4;
    int c = (rr >= 24) ? 1 : 0, q = rr - c * 24;
    int gr = (rowbase + q) & 63;
    float4 v4 = gi4[(c * 64 + gr) * 16 + fw];
    float* d = &img[c][q][fw * 4];
    d[0] = v4.x; d[1] = v4.y; d[2] = v4.z; d[3] = v4.w;
  }
  int iilo = z * 9;
  const float* gf = NtT + (size_t)r * KCP;
  for (int t = tid; t < 162; t += 128){
    int kk = t / 81; int rem4 = t - kk * 81;
    filt4[t] = *(const float4*)(gf + kk * 1296 + iilo * 36 + rem4 * 4);
  }
  __syncthreads();
  int c0 = tid >> 6, hl = (tid >> 2) & 15, w0 = (tid & 3) * 16;
  float acc[16];
  #pragma unroll
  for (int u = 0; u < 16; u++) acc[u] = 0.0f;
  #pragma unroll 1
  for (int kk = 0; kk < 2; kk++){
    int cimg = (c0 - kk + 2) & 1;
    #pragma unroll 1
    for (int iix = 0; iix < 9; iix++){
      const float* ib = img[cimg][hl - iix + 8];       // (h-ii) row
      float v[32];                                     // v[(rel)&31] holds img[w0+rel]
      {
        float4 tm = *(const float4*)&ib[(w0 - 4 + 64) & 63];   // rel -4..-1 -> slots 28..31
        v[28] = tm.x; v[29] = tm.y; v[30] = tm.z; v[31] = tm.w;
      }
      #pragma unroll
      for (int t = 0; t < 4; t++){
        float4 t4 = *(const float4*)&ib[(w0 + 4 * t) & 63];    // rel 0..15
        v[4*t] = t4.x; v[4*t+1] = t4.y; v[4*t+2] = t4.z; v[4*t+3] = t4.w;
      }
      const float4* fb = &filt4[kk * 81 + iix * 9];
      #pragma unroll
      for (int g = 0; g < 9; g++){
        float4 ff = fb[g];
        #pragma unroll
        for (int u = 0; u < 16; u++) acc[u] = fmaf(ff.x, v[(u - (4*g + 0)) & 31], acc[u]);
        #pragma unroll
        for (int u = 0; u < 16; u++) acc[u] = fmaf(ff.y, v[(u - (4*g + 1)) & 31], acc[u]);
        #pragma unroll
        for (int u = 0; u < 16; u++) acc[u] = fmaf(ff.z, v[(u - (4*g + 2)) & 31], acc[u]);
        #pragma unroll
        for (int u = 0; u < 16; u++) acc[u] = fmaf(ff.w, v[(u - (4*g + 3)) & 31], acc[u]);
        if (g < 8){
          float4 nv = *(const float4*)&ib[(w0 - 8 - 4*g + 128) & 63];  // rel -8-4g..-5-4g
          int s = (-8 - 4*g) & 31;
          v[s] = nv.x; v[s+1] = nv.y; v[s+2] = nv.z; v[s+3] = nv.w;
        }
      }
    }
  }
  int h = oct * 16 + hl;
  size_t ob = ((size_t)r + 64 * z) * 8192 + (size_t)(c0 * HW + h * 64 + w0);
  *(float4*)&T1t[ob]      = make_float4(acc[0], acc[1], acc[2], acc[3]);
  *(float4*)&T1t[ob + 4]  = make_float4(acc[4], acc[5], acc[6], acc[7]);
  *(float4*)&T1t[ob + 8]  = make_float4(acc[8], acc[9], acc[10], acc[11]);
  *(float4*)&T1t[ob + 12] = make_float4(acc[12], acc[13], acc[14], acc[15]);
}

// L[p] = clip((inp - S + g*R)/(g+1)); S = (inp - L)/(b+1); R = (1/Kc) * sum_{256 slices} Rpart
__global__ __launch_bounds__(256) void k_reduce_LS(const float* __restrict__ Rpart,
                                                   const float* __restrict__ inp,
                                                   const float* __restrict__ pg, const float* __restrict__ pb,
                                                   float* __restrict__ S, float* __restrict__ Ldst){
  __shared__ float red[8][32];
  int tid = threadIdx.x;
  int pi = tid & 31, sg = tid >> 5;
  int p = blockIdx.x * 32 + pi;
  float acc = 0.0f;
  #pragma unroll 4
  for (int s = sg * 32; s < sg * 32 + 32; s++) acc += Rpart[(size_t)s * 8192 + p];
  red[sg][pi] = acc;
  __syncthreads();
  if (tid < 32){
    float a = 0.0f;
    #pragma unroll
    for (int q = 0; q < 8; q++) a += red[q][pi];
    float R = a * (1.0f / 2592.0f);
    float g = pg[0], b = pb[0];
    float Ln = (inp[p] - S[p] + g * R) / (g + 1.0f);
    Ln = fminf(fmaxf(Ln, 0.0f), 1.0f);
    S[p] = (inp[p] - Ln) / (b + 1.0f);
    Ldst[p] = Ln;
  }
}

// raw gram: out[r1][r2] = dot(rows[r1], rows[r2]) over len4 float4s (row stride in floats)
__global__ __launch_bounds__(64) void k_gram(const float* __restrict__ rows, int stride, int len4,
                                             float* __restrict__ out){
  int e = blockIdx.x; int r1 = e >> 6, r2 = e & 63;
  if (r2 < r1) return;
  int lane = threadIdx.x;
  const float4* a = (const float4*)(rows + (size_t)r1 * stride);
  const float4* b = (const float4*)(rows + (size_t)r2 * stride);
  float acc = 0.0f;
  for (int p = lane; p < len4; p += 64){
    float4 x = a[p], y = b[p];
    acc = fmaf(x.x, y.x, acc); acc = fmaf(x.y, y.y, acc);
    acc = fmaf(x.z, y.z, acc); acc = fmaf(x.w, y.w, acc);
  }
  for (int off = 32; off; off >>= 1) acc += __shfl_down(acc, off, 64);
  if (lane == 0){ out[r1 * 64 + r2] = acc; out[r2 * 64 + r1] = acc; }
}

// Mt_new[sbase+s][p] = 2g * sum_{r<64} (sum_z T1t[r+64z][p]) * CmInv[r][sbase+s]
__global__ __launch_bounds__(256) void k_mn(const float* __restrict__ T1t, const float* __restrict__ CmInv,
                                            const float* __restrict__ pg, float* __restrict__ Mt){
  __shared__ float4 ci4[1024];
  int tid = threadIdx.x;
  const float4* g4 = (const float4*)CmInv;
  for (int t = tid; t < 1024; t += 256) ci4[t] = g4[t];
  __syncthreads();
  int p = blockIdx.x * 256 + tid;
  int sbase = blockIdx.y * 32;
  float g2 = 2.0f * pg[0];
  float acc[32];
  #pragma unroll
  for (int s = 0; s < 32; s++) acc[s] = 0.0f;
  for (int r = 0; r < 64; r++){
    float v = T1t[(size_t)r * 8192 + p] + T1t[(size_t)(r + 64) * 8192 + p]
            + T1t[(size_t)(r + 128) * 8192 + p] + T1t[(size_t)(r + 192) * 8192 + p];
    #pragma unroll
    for (int k = 0; k < 8; k++){
      float4 c = ci4[r * 16 + (sbase >> 2) + k];
      acc[4*k+0] = fmaf(v, c.x, acc[4*k+0]);
      acc[4*k+1] = fmaf(v, c.y, acc[4*k+1]);
      acc[4*k+2] = fmaf(v, c.z, acc[4*k+2]);
      acc[4*k+3] = fmaf(v, c.w, acc[4*k+3]);
    }
  }
  #pragma unroll
  for (int s = 0; s < 32; s++) Mt[(size_t)(sbase + s) * 8192 + p] = g2 * acc[s];
}

// T2part[hc][r][col] (+ fused FULL inv(Cn) as sentinel y==8, single-wave barrier-free)
__global__ __launch_bounds__(256) void k_conv_T2(const float* __restrict__ Lg,
                                                 const float* __restrict__ Mtg,
                                                 float* __restrict__ T2part,
                                                 const float* __restrict__ Gr,
                                                 const float* __restrict__ pg,
                                                 const float* __restrict__ pa,
                                                 float* __restrict__ CnI){
  __shared__ float smem[9728];   // union: conv uses 9728 floats (Mi 8704 + Ls4 1024); inv A uses 4096
  if (blockIdx.y == 8){
    if (blockIdx.x == 0 && threadIdx.x < 64)
      inv64_wave(Gr, pg, pa, CnI, threadIdx.x, smem);
    return;
  }
  float* Mi = smem;                                    // [128*68]
  float4* Ls4 = (float4*)(smem + 8704);                // [256], byte offset 34816 (16B aligned)
  int r = blockIdx.x, hc = blockIdx.y, tid = threadIdx.x;
  const float4* gm4 = (const float4*)(Mtg + (size_t)r * 8192);
  for (int t = tid; t < 2048; t += 256){
    float4 v4 = gm4[t];
    int row = t >> 4, cb = (t & 15) * 4;
    float* d = &Mi[row * 68 + cb];
    d[0] = v4.x; d[1] = v4.y; d[2] = v4.z; d[3] = v4.w;
  }
  const float4* gl4 = (const float4*)Lg;
  if (tid < 256){
    int c = tid >> 7, rem = tid & 127;
    Ls4[tid] = gl4[c * 1024 + hc * 128 + rem];
  }
  __syncthreads();
  if (tid >= 216) return;
  int kk = tid / 108, rest = tid % 108, ii = rest / 3, jj0 = (rest % 3) * 12;
  float acc[12];
  #pragma unroll
  for (int u = 0; u < 12; u++) acc[u] = 0.0f;
  #pragma unroll 1
  for (int c = 0; c < 2; c++){
    #pragma unroll 1
    for (int hl = 0; hl < 8; hl++){
      int h = hc * 8 + hl;
      const float* ib = &Mi[(((c + kk) & 1) * 64 + ((h + ii) & 63)) * 68];
      const float4* lrow = &Ls4[c * 128 + hl * 16];
      float v[16];
      {
        float4 t0 = *(const float4*)&ib[jj0];
        float4 t1 = *(const float4*)&ib[jj0 + 4];
        float4 t2 = *(const float4*)&ib[jj0 + 8];
        float4 t3 = *(const float4*)&ib[jj0 + 12];
        v[0]=t0.x; v[1]=t0.y; v[2]=t0.z; v[3]=t0.w;
        v[4]=t1.x; v[5]=t1.y; v[6]=t1.z; v[7]=t1.w;
        v[8]=t2.x; v[9]=t2.y; v[10]=t2.z; v[11]=t2.w;
        v[12]=t3.x; v[13]=t3.y; v[14]=t3.z; v[15]=t3.w;
      }
      #pragma unroll
      for (int wg = 0; wg < 16; wg++){
        float4 lv = lrow[wg];
        #pragma unroll
        for (int u = 0; u < 12; u++) acc[u] = fmaf(lv.x, v[(4*wg + 0 + u) & 15], acc[u]);
        #pragma unroll
        for (int u = 0; u < 12; u++) acc[u] = fmaf(lv.y, v[(4*wg + 1 + u) & 15], acc[u]);
        #pragma unroll
        for (int u = 0; u < 12; u++) acc[u] = fmaf(lv.z, v[(4*wg + 2 + u) & 15], acc[u]);
        #pragma unroll
        for (int u = 0; u < 12; u++) acc[u] = fmaf(lv.w, v[(4*wg + 3 + u) & 15], acc[u]);
        if (wg < 15){
          float4 nv = *(const float4*)&ib[(jj0 + 4*wg + 16) & 63];
          int s = (4*wg) & 15;
          v[s] = nv.x; v[s+1] = nv.y; v[s+2] = nv.z; v[s+3] = nv.w;
        }
      }
    }
  }
  #pragma unroll
  for (int u = 0; u < 12; u++){
    int col = kk * 1296 + (jj0 + u) * 36 + ii;
    T2part[((size_t)hc * 64 + r) * KC + col] = acc[u];
  }
}

// T2sum[t] = sum_hc T2part[hc*165888 + t]   (t = r*KC+col)
__global__ __launch_bounds__(256) void k_t2sum(const float* __restrict__ T2part, float* __restrict__ T2sum){
  int t = blockIdx.x * 256 + threadIdx.x;
  float s = 0.0f;
  #pragma unroll
  for (int hc = 0; hc < 8; hc++) s += T2part[(size_t)hc * 165888 + t];
  T2sum[t] = s;
}

// NtT[rr][d(col)] = 2g * sum_s CnInv[s][rr] * T2sum[s][col], rr in 16-chunk per blockIdx.y
__global__ __launch_bounds__(256) void k_nn(const float* __restrict__ T2sum, const float* __restrict__ CnInv,
                                            const float* __restrict__ pg,
                                            float* __restrict__ NtT){
  __shared__ float4 ci4[1024];
  int tid = threadIdx.x;
  const float4* g4 = (const float4*)CnInv;
  for (int t = tid; t < 1024; t += 256) ci4[t] = g4[t];
  __syncthreads();
  int col = blockIdx.x * 256 + tid;
  if (col >= KC) return;
  int rb = blockIdx.y * 16;
  float g2 = 2.0f * pg[0];
  float acc[16];
  #pragma unroll
  for (int rr = 0; rr < 16; rr++) acc[rr] = 0.0f;
  for (int s = 0; s < 64; s++){
    float tv = T2sum[(size_t)s * KC + col];
    #pragma unroll
    for (int k = 0; k < 4; k++){
      float4 c = ci4[s * 16 + (rb >> 2) + k];
      acc[4*k+0] = fmaf(tv, c.x, acc[4*k+0]);
      acc[4*k+1] = fmaf(tv, c.y, acc[4*k+1]);
      acc[4*k+2] = fmaf(tv, c.z, acc[4*k+2]);
      acc[4*k+3] = fmaf(tv, c.w, acc[4*k+3]);
    }
  }
  int kk = col / 1296, rest = col % 1296, jj = rest / 36, iv = rest % 36;
  int d = (kk * 36 + iv) * 36 + jj;
  #pragma unroll
  for (int rr = 0; rr < 16; rr++){
    NtT[(size_t)(rb + rr) * KCP + d] = g2 * acc[rr];
  }
}

extern "C" void kernel_launch(void* const* d_in, const int* in_sizes, int n_in,
                              void* d_out, int out_size, void* d_ws, size_t ws_size,
                              hipStream_t stream) {
  const float* inp = (const float*)d_in[0];
  const float* s0  = (const float*)d_in[1];
  const float* pa  = (const float*)d_in[2];
  const float* pb  = (const float*)d_in[3];
  const float* pg  = (const float*)d_in[4];
  float* ws  = (float*)d_ws;
  float* L   = ws + OFF_L;   float* S   = ws + OFF_S;    float* Mt  = ws + OFF_MT;
  float* NtT = ws + OFF_NTT; float* Big = ws + OFF_BIG;
  float* T2p = ws + OFF_BIG;              // aliased into Big (disjoint lifetimes)
  float* T2s = ws + OFF_BIG + 1327104u;   // aliased into Big
  float* Gr  = ws + OFF_GRAM;
  float* CmI = ws + OFF_CMI; float* CnI = ws + OFF_CNI;
  float* out = (float*)d_out;

  k_init<<<2048, 256, 0, stream>>>(inp, s0, L, S, Mt, NtT);
  for (int step = 0; step < 5; step++){
    bool last = (step == 4);
    if (!last)
      k_gram<<<4096, 64, 0, stream>>>(NtT, KCP, KCP / 4, Gr);   // Cm raw = N@N^T (pad zeros)
    // conv_R grid z==4 (non-last steps) carries FULL inv(Cm) -> CmI (single-wave, barrier-free)
    k_conv_R<<<dim3(64, 4, last ? 4 : 5), 128, 0, stream>>>(Mt, NtT, Big, Gr, pg, pa, CmI);
    k_reduce_LS<<<256, 256, 0, stream>>>(Big, inp, pg, pb, S, last ? out : L);
    if (last) break;
    k_conv_T1<<<dim3(64, 4, 4), 128, 0, stream>>>(L, NtT, Big);
    k_mn<<<dim3(32, 2), 256, 0, stream>>>(Big, CmI, pg, Mt);
    k_gram<<<4096, 64, 0, stream>>>(Mt, 8192, 2048, Gr);        // Cn raw = Mn^T@Mn
    // conv_T2 grid y==8 carries FULL inv(Cn) -> CnI (single-wave, barrier-free)
    k_conv_T2<<<dim3(64, 9), 256, 0, stream>>>(L, Mt, T2p, Gr, pg, pa, CnI);
    k_t2sum<<<648, 256, 0, stream>>>(T2p, T2s);
    k_nn<<<dim3(11, 4), 256, 0, stream>>>(T2s, CnI, pg, NtT);
  }
}

// Round 15
// 1148.119 us; speedup vs baseline: 2.3499x; 2.3499x over previous
//
#include <hip/hip_runtime.h>

// Problem constants: B=1, C=2, H=W=64, m=8192, mk=64, K1=K2=36, K3=2, Kc=2592, iters=6 (5 steps).
#define KC 2592
#define KCP 2624           // padded NtT row stride (zeros in tail)
#define HW 4096

// workspace layout (float offsets), total 2818048 floats = 11.27 MB
#define OFF_L    0u
#define OFF_S    8192u
#define OFF_MT   16384u    // Mt[64][8192]
#define OFF_NTT  540672u   // NtT[64][2624], layout d=(kk*36+ii)*36+jj, cols 2592..2623 zero
#define OFF_BIG  708608u   // Rpart[256][8192] / T1t[256][8192] / (T2part[8][64][2592] + T2sum[64][2592])
#define OFF_GRAM 2805760u  // raw gram 64x64 (shared by Cm and Cn phases)
#define OFF_CMI  2809856u
#define OFF_CNI  2813952u

__global__ __launch_bounds__(256) void k_init(const float* __restrict__ inp, const float* __restrict__ s0,
                                              float* __restrict__ L, float* __restrict__ S,
                                              float* __restrict__ Mt, float* __restrict__ NtT){
  int t = blockIdx.x * 256 + threadIdx.x;
  if (t < 8192){ L[t] = inp[t]; S[t] = s0[t]; }
  if (t < 524288){ int r = t >> 13; int p = t & 8191; Mt[t] = (p == r) ? 1.0f : 0.0f; }
  if (t < 167936){ int r = t / KCP; int d = t - r * KCP;
                   int dr = (r % 36) * 36 + r / 36;   // N0: d=(0*36+ii)*36+jj with col=jj*36+ii=r
                   NtT[t] = (d == dr) ? 1.0f : 0.0f; }
}

// ---- STANDALONE rolled LDS Jordan-exchange inverse of (2g*gram + a*I), SPD, no pivoting.
// Final synthesis of R5-R14: (a) fusing ANY LDS-using inv into a conv kernel wrecks the host's
// codegen (R11-R14: VGPR 76->52/64, 28->177/291us — alias loss via divergent smem union);
// (b) register-only hosted inv preserves host codegen but costs ~1.3us/pivot (R8-R10, ~90us/
// step inflation); (c) unrolled straight-line bodies icache-stream (~9cyc/instr, R6); (d) R1's
// 249us standalone was a serialized dynamic-RMW loop. This kernel: OWN launch (no host to
// wreck), ROLLED j-loop (~2KB code, icache-resident), 2 barriers + 16 INDEPENDENT LDS-RMW per
// thread per pivot (latency pipelined) -> ~33k cyc =~ 25-40us even at droop clock.
// Math identical to R12/R13's verified Jordan exchange (both PASSed absmax 9.8e-4).
__global__ __launch_bounds__(256) void k_inv(const float* __restrict__ src,
                                             const float* __restrict__ pg,
                                             const float* __restrict__ pa,
                                             float* __restrict__ dst){
  __shared__ float A[64 * 65];
  __shared__ float rowj[64];
  __shared__ float colj[64];
  int tid = threadIdx.x;
  float scale = 2.0f * pg[0], ad = pa[0];
  for (int t = tid; t < 4096; t += 256){
    int i = t >> 6, c = t & 63;
    A[i * 65 + c] = scale * src[t] + ((i == c) ? ad : 0.0f);
  }
  __syncthreads();
  int c = tid & 63, q = tid >> 6;   // q in 0..3, 16 rows each
  int i0 = q * 16;
  #pragma unroll 1
  for (int j = 0; j < 64; j++){
    if (tid < 64) rowj[tid] = A[j * 65 + tid];                    // old row j
    else if (tid < 128) colj[tid - 64] = A[(tid - 64) * 65 + j];  // old col j
    __syncthreads();
    float p = 1.0f / rowj[j];
    float rc = rowj[c];
    bool cj = (c == j);
    float rcp = rc * p;
    #pragma unroll 8
    for (int r = 0; r < 16; r++){
      int i = i0 + r;
      float old = A[i * 65 + c];
      float fi = colj[i];
      float nonpiv = cj ? (-fi * p) : fmaf(-fi, rcp, old); // i!=j: col j -> -A[i][j]p else -= A[i][j]p*A[j][c]
      float pivrow = cj ? p : rcp;                         // i==j: diag -> p else A[j][c]*p
      A[i * 65 + c] = (i == j) ? pivrow : nonpiv;
    }
    __syncthreads();
  }
  for (int t = tid; t < 4096; t += 256)
    dst[t] = A[(t >> 6) * 65 + (t & 63)];
}

// ---- conv_R (PURE): Rpart[r+64z][p] = sum_{kk, ii in 9-quarter z, jj}
//      Mt[r][(c+kk)%2][(h+ii)%64][(w+jj)%64] * f[kk][ii][jj]
// 128 thr = 2c x 16h x 4wq; 16 outputs/thread; LDS holds only the 24 needed rows per c.
__global__ __launch_bounds__(128) void k_conv_R(const float* __restrict__ Mtg,
                                                const float* __restrict__ NtT,
                                                float* __restrict__ Rpart){
  __shared__ float img[2][24][68];
  __shared__ float4 filt4[162];
  int r = blockIdx.x, oct = blockIdx.y, z = blockIdx.z, tid = threadIdx.x;
  int rowbase = oct * 16 + z * 9;
  const float4* gi4 = (const float4*)(Mtg + (size_t)r * 8192);
  for (int t = tid; t < 768; t += 128){
    int fw = t & 15, rr = t >> 4;
    int c = (rr >= 24) ? 1 : 0, q = rr - c * 24;
    int gr = (rowbase + q) & 63;
    float4 v4 = gi4[(c * 64 + gr) * 16 + fw];
    float* d = &img[c][q][fw * 4];
    d[0] = v4.x; d[1] = v4.y; d[2] = v4.z; d[3] = v4.w;
  }
  int iilo = z * 9;
  const float* gf = NtT + (size_t)r * KCP;
  for (int t = tid; t < 162; t += 128){
    int kk = t / 81; int rem4 = t - kk * 81;
    filt4[t] = *(const float4*)(gf + kk * 1296 + iilo * 36 + rem4 * 4);
  }
  __syncthreads();
  int c0 = tid >> 6, hl = (tid >> 2) & 15, w0 = (tid & 3) * 16;
  float acc[16];
  #pragma unroll
  for (int u = 0; u < 16; u++) acc[u] = 0.0f;
  #pragma unroll 1
  for (int kk = 0; kk < 2; kk++){
    int cimg = (c0 + kk) & 1;
    #pragma unroll 1
    for (int iix = 0; iix < 9; iix++){
      const float* ib = img[cimg][hl + iix];
      float v[32];
      #pragma unroll
      for (int t = 0; t < 8; t++){
        float4 t4 = *(const float4*)&ib[(w0 + 4 * t) & 63];
        v[4*t] = t4.x; v[4*t+1] = t4.y; v[4*t+2] = t4.z; v[4*t+3] = t4.w;
      }
      const float4* fb = &filt4[kk * 81 + iix * 9];
      #pragma unroll
      for (int g = 0; g < 9; g++){
        float4 ff = fb[g];
        #pragma unroll
        for (int u = 0; u < 16; u++) acc[u] = fmaf(ff.x, v[(4*g + 0 + u) & 31], acc[u]);
        #pragma unroll
        for (int u = 0; u < 16; u++) acc[u] = fmaf(ff.y, v[(4*g + 1 + u) & 31], acc[u]);
        #pragma unroll
        for (int u = 0; u < 16; u++) acc[u] = fmaf(ff.z, v[(4*g + 2 + u) & 31], acc[u]);
        #pragma unroll
        for (int u = 0; u < 16; u++) acc[u] = fmaf(ff.w, v[(4*g + 3 + u) & 31], acc[u]);
        if (g < 5){
          float4 nv = *(const float4*)&ib[(w0 + 32 + 4*g) & 63];
          int s = (4*g) & 31;
          v[s] = nv.x; v[s+1] = nv.y; v[s+2] = nv.z; v[s+3] = nv.w;
        }
      }
    }
  }
  int h = oct * 16 + hl;
  size_t ob = ((size_t)r + 64 * z) * 8192 + (size_t)(c0 * HW + h * 64 + w0);
  *(float4*)&Rpart[ob]      = make_float4(acc[0], acc[1], acc[2], acc[3]);
  *(float4*)&Rpart[ob + 4]  = make_float4(acc[4], acc[5], acc[6], acc[7]);
  *(float4*)&Rpart[ob + 8]  = make_float4(acc[8], acc[9], acc[10], acc[11]);
  *(float4*)&Rpart[ob + 12] = make_float4(acc[12], acc[13], acc[14], acc[15]);
}

// ---- conv_T1 (PURE): T1t[r+64z][p] = sum L[(c-kk)%2][(h-ii)%64][(w-jj)%64] * f[kk][ii][jj]
__global__ __launch_bounds__(128) void k_conv_T1(const float* __restrict__ Lg,
                                                 const float* __restrict__ NtT,
                                                 float* __restrict__ T1t){
  __shared__ float img[2][24][68];
  __shared__ float4 filt4[162];
  int r = blockIdx.x, oct = blockIdx.y, z = blockIdx.z, tid = threadIdx.x;
  int rowbase = (oct * 16 - z * 9 - 8 + 128) & 63;     // stored q <-> global row (rowbase+q)&63
  const float4* gi4 = (const float4*)Lg;
  for (int t = tid; t < 768; t += 128){
    int fw = t & 15, rr = t >> 4;
    int c = (rr >= 24) ? 1 : 0, q = rr - c * 24;
    int gr = (rowbase + q) & 63;
    float4 v4 = gi4[(c * 64 + gr) * 16 + fw];
    float* d = &img[c][q][fw * 4];
    d[0] = v4.x; d[1] = v4.y; d[2] = v4.z; d[3] = v4.w;
  }
  int iilo = z * 9;
  const float* gf = NtT + (size_t)r * KCP;
  for (int t = tid; t < 162; t += 128){
    int kk = t / 81; int rem4 = t - kk * 81;
    filt4[t] = *(const float4*)(gf + kk * 1296 + iilo * 36 + rem4 * 4);
  }
  __syncthreads();
  int c0 = tid >> 6, hl = (tid >> 2) & 15, w0 = (tid & 3) * 16;
  float acc[16];
  #pragma unroll
  for (int u = 0; u < 16; u++) acc[u] = 0.0f;
  #pragma unroll 1
  for (int kk = 0; kk < 2; kk++){
    int cimg = (c0 - kk + 2) & 1;
    #pragma unroll 1
    for (int iix = 0; iix < 9; iix++){
      const float* ib = img[cimg][hl - iix + 8];       // (h-ii) row
      float v[32];                                     // v[(rel)&31] holds img[w0+rel]
      {
        float4 tm = *(const float4*)&ib[(w0 - 4 + 64) & 63];   // rel -4..-1 -> slots 28..31
        v[28] = tm.x; v[29] = tm.y; v[30] = tm.z; v[31] = tm.w;
      }
      #pragma unroll
      for (int t = 0; t < 4; t++){
        float4 t4 = *(const float4*)&ib[(w0 + 4 * t) & 63];    // rel 0..15
        v[4*t] = t4.x; v[4*t+1] = t4.y; v[4*t+2] = t4.z; v[4*t+3] = t4.w;
      }
      const float4* fb = &filt4[kk * 81 + iix * 9];
      #pragma unroll
      for (int g = 0; g < 9; g++){
        float4 ff = fb[g];
        #pragma unroll
        for (int u = 0; u < 16; u++) acc[u] = fmaf(ff.x, v[(u - (4*g + 0)) & 31], acc[u]);
        #pragma unroll
        for (int u = 0; u < 16; u++) acc[u] = fmaf(ff.y, v[(u - (4*g + 1)) & 31], acc[u]);
        #pragma unroll
        for (int u = 0; u < 16; u++) acc[u] = fmaf(ff.z, v[(u - (4*g + 2)) & 31], acc[u]);
        #pragma unroll
        for (int u = 0; u < 16; u++) acc[u] = fmaf(ff.w, v[(u - (4*g + 3)) & 31], acc[u]);
        if (g < 8){
          float4 nv = *(const float4*)&ib[(w0 - 8 - 4*g + 128) & 63];  // rel -8-4g..-5-4g
          int s = (-8 - 4*g) & 31;
          v[s] = nv.x; v[s+1] = nv.y; v[s+2] = nv.z; v[s+3] = nv.w;
        }
      }
    }
  }
  int h = oct * 16 + hl;
  size_t ob = ((size_t)r + 64 * z) * 8192 + (size_t)(c0 * HW + h * 64 + w0);
  *(float4*)&T1t[ob]      = make_float4(acc[0], acc[1], acc[2], acc[3]);
  *(float4*)&T1t[ob + 4]  = make_float4(acc[4], acc[5], acc[6], acc[7]);
  *(float4*)&T1t[ob + 8]  = make_float4(acc[8], acc[9], acc[10], acc[11]);
  *(float4*)&T1t[ob + 12] = make_float4(acc[12], acc[13], acc[14], acc[15]);
}

// L[p] = clip((inp - S + g*R)/(g+1)); S = (inp - L)/(b+1); R = (1/Kc) * sum_{256 slices} Rpart
__global__ __launch_bounds__(256) void k_reduce_LS(const float* __restrict__ Rpart,
                                                   const float* __restrict__ inp,
                                                   const float* __restrict__ pg, const float* __restrict__ pb,
                                                   float* __restrict__ S, float* __restrict__ Ldst){
  __shared__ float red[8][32];
  int tid = threadIdx.x;
  int pi = tid & 31, sg = tid >> 5;
  int p = blockIdx.x * 32 + pi;
  float acc = 0.0f;
  #pragma unroll 4
  for (int s = sg * 32; s < sg * 32 + 32; s++) acc += Rpart[(size_t)s * 8192 + p];
  red[sg][pi] = acc;
  __syncthreads();
  if (tid < 32){
    float a = 0.0f;
    #pragma unroll
    for (int q = 0; q < 8; q++) a += red[q][pi];
    float R = a * (1.0f / 2592.0f);
    float g = pg[0], b = pb[0];
    float Ln = (inp[p] - S[p] + g * R) / (g + 1.0f);
    Ln = fminf(fmaxf(Ln, 0.0f), 1.0f);
    S[p] = (inp[p] - Ln) / (b + 1.0f);
    Ldst[p] = Ln;
  }
}

// raw gram: out[r1][r2] = dot(rows[r1], rows[r2]) over len4 float4s (row stride in floats)
__global__ __launch_bounds__(64) void k_gram(const float* __restrict__ rows, int stride, int len4,
                                             float* __restrict__ out){
  int e = blockIdx.x; int r1 = e >> 6, r2 = e & 63;
  if (r2 < r1) return;
  int lane = threadIdx.x;
  const float4* a = (const float4*)(rows + (size_t)r1 * stride);
  const float4* b = (const float4*)(rows + (size_t)r2 * stride);
  float acc = 0.0f;
  for (int p = lane; p < len4; p += 64){
    float4 x = a[p], y = b[p];
    acc = fmaf(x.x, y.x, acc); acc = fmaf(x.y, y.y, acc);
    acc = fmaf(x.z, y.z, acc); acc = fmaf(x.w, y.w, acc);
  }
  for (int off = 32; off; off >>= 1) acc += __shfl_down(acc, off, 64);
  if (lane == 0){ out[r1 * 64 + r2] = acc; out[r2 * 64 + r1] = acc; }
}

// Mt_new[sbase+s][p] = 2g * sum_{r<64} (sum_z T1t[r+64z][p]) * CmInv[r][sbase+s]
__global__ __launch_bounds__(256) void k_mn(const float* __restrict__ T1t, const float* __restrict__ CmInv,
                                            const float* __restrict__ pg, float* __restrict__ Mt){
  __shared__ float4 ci4[1024];
  int tid = threadIdx.x;
  const float4* g4 = (const float4*)CmInv;
  for (int t = tid; t < 1024; t += 256) ci4[t] = g4[t];
  __syncthreads();
  int p = blockIdx.x * 256 + tid;
  int sbase = blockIdx.y * 32;
  float g2 = 2.0f * pg[0];
  float acc[32];
  #pragma unroll
  for (int s = 0; s < 32; s++) acc[s] = 0.0f;
  for (int r = 0; r < 64; r++){
    float v = T1t[(size_t)r * 8192 + p] + T1t[(size_t)(r + 64) * 8192 + p]
            + T1t[(size_t)(r + 128) * 8192 + p] + T1t[(size_t)(r + 192) * 8192 + p];
    #pragma unroll
    for (int k = 0; k < 8; k++){
      float4 c = ci4[r * 16 + (sbase >> 2) + k];
      acc[4*k+0] = fmaf(v, c.x, acc[4*k+0]);
      acc[4*k+1] = fmaf(v, c.y, acc[4*k+1]);
      acc[4*k+2] = fmaf(v, c.z, acc[4*k+2]);
      acc[4*k+3] = fmaf(v, c.w, acc[4*k+3]);
    }
  }
  #pragma unroll
  for (int s = 0; s < 32; s++) Mt[(size_t)(sbase + s) * 8192 + p] = g2 * acc[s];
}

// ---- conv_T2 (PURE): T2part[hc][r][col] = sum_{c, h in 8-row chunk hc, w}
//      L[c][h][w] * Mt[r][(c+kk)%2][(h+ii)%64][(w+jj)%64]
__global__ __launch_bounds__(256) void k_conv_T2(const float* __restrict__ Lg,
                                                 const float* __restrict__ Mtg,
                                                 float* __restrict__ T2part){
  __shared__ float Mi[128 * 68];
  __shared__ float4 Ls4[256];
  int r = blockIdx.x, hc = blockIdx.y, tid = threadIdx.x;
  const float4* gm4 = (const float4*)(Mtg + (size_t)r * 8192);
  for (int t = tid; t < 2048; t += 256){
    float4 v4 = gm4[t];
    int row = t >> 4, cb = (t & 15) * 4;
    float* d = &Mi[row * 68 + cb];
    d[0] = v4.x; d[1] = v4.y; d[2] = v4.z; d[3] = v4.w;
  }
  const float4* gl4 = (const float4*)Lg;
  if (tid < 256){
    int c = tid >> 7, rem = tid & 127;
    Ls4[tid] = gl4[c * 1024 + hc * 128 + rem];
  }
  __syncthreads();
  if (tid >= 216) return;
  int kk = tid / 108, rest = tid % 108, ii = rest / 3, jj0 = (rest % 3) * 12;
  float acc[12];
  #pragma unroll
  for (int u = 0; u < 12; u++) acc[u] = 0.0f;
  #pragma unroll 1
  for (int c = 0; c < 2; c++){
    #pragma unroll 1
    for (int hl = 0; hl < 8; hl++){
      int h = hc * 8 + hl;
      const float* ib = &Mi[(((c + kk) & 1) * 64 + ((h + ii) & 63)) * 68];
      const float4* lrow = &Ls4[c * 128 + hl * 16];
      float v[16];
      {
        float4 t0 = *(const float4*)&ib[jj0];
        float4 t1 = *(const float4*)&ib[jj0 + 4];
        float4 t2 = *(const float4*)&ib[jj0 + 8];
        float4 t3 = *(const float4*)&ib[jj0 + 12];
        v[0]=t0.x; v[1]=t0.y; v[2]=t0.z; v[3]=t0.w;
        v[4]=t1.x; v[5]=t1.y; v[6]=t1.z; v[7]=t1.w;
        v[8]=t2.x; v[9]=t2.y; v[10]=t2.z; v[11]=t2.w;
        v[12]=t3.x; v[13]=t3.y; v[14]=t3.z; v[15]=t3.w;
      }
      #pragma unroll
      for (int wg = 0; wg < 16; wg++){
        float4 lv = lrow[wg];
        #pragma unroll
        for (int u = 0; u < 12; u++) acc[u] = fmaf(lv.x, v[(4*wg + 0 + u) & 15], acc[u]);
        #pragma unroll
        for (int u = 0; u < 12; u++) acc[u] = fmaf(lv.y, v[(4*wg + 1 + u) & 15], acc[u]);
        #pragma unroll
        for (int u = 0; u < 12; u++) acc[u] = fmaf(lv.z, v[(4*wg + 2 + u) & 15], acc[u]);
        #pragma unroll
        for (int u = 0; u < 12; u++) acc[u] = fmaf(lv.w, v[(4*wg + 3 + u) & 15], acc[u]);
        if (wg < 15){
          float4 nv = *(const float4*)&ib[(jj0 + 4*wg + 16) & 63];
          int s = (4*wg) & 15;
          v[s] = nv.x; v[s+1] = nv.y; v[s+2] = nv.z; v[s+3] = nv.w;
        }
      }
    }
  }
  #pragma unroll
  for (int u = 0; u < 12; u++){
    int col = kk * 1296 + (jj0 + u) * 36 + ii;
    T2part[((size_t)hc * 64 + r) * KC + col] = acc[u];
  }
}

// T2sum[t] = sum_hc T2part[hc*165888 + t]   (t = r*KC+col)
__global__ __launch_bounds__(256) void k_t2sum(const float* __restrict__ T2part, float* __restrict__ T2sum){
  int t = blockIdx.x * 256 + threadIdx.x;
  float s = 0.0f;
  #pragma unroll
  for (int hc = 0; hc < 8; hc++) s += T2part[(size_t)hc * 165888 + t];
  T2sum[t] = s;
}

// NtT[rr][d(col)] = 2g * sum_s CnInv[s][rr] * T2sum[s][col], rr in 16-chunk per blockIdx.y
__global__ __launch_bounds__(256) void k_nn(const float* __restrict__ T2sum, const float* __restrict__ CnInv,
                                            const float* __restrict__ pg,
                                            float* __restrict__ NtT){
  __shared__ float4 ci4[1024];
  int tid = threadIdx.x;
  const float4* g4 = (const float4*)CnInv;
  for (int t = tid; t < 1024; t += 256) ci4[t] = g4[t];
  __syncthreads();
  int col = blockIdx.x * 256 + tid;
  if (col >= KC) return;
  int rb = blockIdx.y * 16;
  float g2 = 2.0f * pg[0];
  float acc[16];
  #pragma unroll
  for (int rr = 0; rr < 16; rr++) acc[rr] = 0.0f;
  for (int s = 0; s < 64; s++){
    float tv = T2sum[(size_t)s * KC + col];
    #pragma unroll
    for (int k = 0; k < 4; k++){
      float4 c = ci4[s * 16 + (rb >> 2) + k];
      acc[4*k+0] = fmaf(tv, c.x, acc[4*k+0]);
      acc[4*k+1] = fmaf(tv, c.y, acc[4*k+1]);
      acc[4*k+2] = fmaf(tv, c.z, acc[4*k+2]);
      acc[4*k+3] = fmaf(tv, c.w, acc[4*k+3]);
    }
  }
  int kk = col / 1296, rest = col % 1296, jj = rest / 36, iv = rest % 36;
  int d = (kk * 36 + iv) * 36 + jj;
  #pragma unroll
  for (int rr = 0; rr < 16; rr++){
    NtT[(size_t)(rb + rr) * KCP + d] = g2 * acc[rr];
  }
}

extern "C" void kernel_launch(void* const* d_in, const int* in_sizes, int n_in,
                              void* d_out, int out_size, void* d_ws, size_t ws_size,
                              hipStream_t stream) {
  const float* inp = (const float*)d_in[0];
  const float* s0  = (const float*)d_in[1];
  const float* pa  = (const float*)d_in[2];
  const float* pb  = (const float*)d_in[3];
  const float* pg  = (const float*)d_in[4];
  float* ws  = (float*)d_ws;
  float* L   = ws + OFF_L;   float* S   = ws + OFF_S;    float* Mt  = ws + OFF_MT;
  float* NtT = ws + OFF_NTT; float* Big = ws + OFF_BIG;
  float* T2p = ws + OFF_BIG;              // aliased into Big (disjoint lifetimes)
  float* T2s = ws + OFF_BIG + 1327104u;   // aliased into Big
  float* Gr  = ws + OFF_GRAM;
  float* CmI = ws + OFF_CMI; float* CnI = ws + OFF_CNI;
  float* out = (float*)d_out;

  k_init<<<2048, 256, 0, stream>>>(inp, s0, L, S, Mt, NtT);
  for (int step = 0; step < 5; step++){
    bool last = (step == 4);
    k_conv_R<<<dim3(64, 4, 4), 128, 0, stream>>>(Mt, NtT, Big);
    k_reduce_LS<<<256, 256, 0, stream>>>(Big, inp, pg, pb, S, last ? out : L);
    if (last) break;
    k_gram<<<4096, 64, 0, stream>>>(NtT, KCP, KCP / 4, Gr);   // Cm raw = N@N^T (pad zeros)
    k_inv<<<1, 256, 0, stream>>>(Gr, pg, pa, CmI);
    k_conv_T1<<<dim3(64, 4, 4), 128, 0, stream>>>(L, NtT, Big);
    k_mn<<<dim3(32, 2), 256, 0, stream>>>(Big, CmI, pg, Mt);
    k_gram<<<4096, 64, 0, stream>>>(Mt, 8192, 2048, Gr);      // Cn raw = Mn^T@Mn
    k_inv<<<1, 256, 0, stream>>>(Gr, pg, pa, CnI);
    k_conv_T2<<<dim3(64, 8), 256, 0, stream>>>(L, Mt, T2p);
    k_t2sum<<<648, 256, 0, stream>>>(T2p, T2s);
    k_nn<<<dim3(11, 4), 256, 0, stream>>>(T2s, CnI, pg, NtT);
  }
}